// Round 9
// baseline (722.774 us; speedup 1.0000x reference)
//
#include <hip/hip_runtime.h>
#include <hip/hip_bf16.h>
#include <stdint.h>

// LNLinearSigmoid: LayerNorm(x) @ W^T -> sigmoid
// Round 9: fuse LN into the GEMM. GEMM computes raw bf16(x) @ Wb^T with
// epilogue correction y = rs_r*(acc - mu_r*wsum_c); row stats computed for
// free during A reg-staging (x fp32 -> cvt -> swizzled ds_write), B staged
// via async16 as before. Eliminates the 32us xn materialization pass.
// 8 waves, 256x256 tile, BK=64, 1 barrier + vmcnt(0) per K-tile.
// ws usage: Wb 8.4MB + wsum 8KB.

typedef __attribute__((ext_vector_type(4))) float f32x4;
typedef __attribute__((ext_vector_type(8))) __bf16 b16x8;
typedef __attribute__((ext_vector_type(4))) __bf16 b16x4;

__device__ __forceinline__ void async16(void* lds_p, const void* g) {
  __builtin_amdgcn_global_load_lds(
      (const __attribute__((address_space(1))) void*)g,
      (__attribute__((address_space(3))) void*)lds_p, 16, 0, 0);
}

__device__ __forceinline__ unsigned short f2bf(float f) {
  uint32_t u = __float_as_uint(f);
  u += 0x7FFFu + ((u >> 16) & 1u);
  return (unsigned short)(u >> 16);
}

// ---------------- W fp32 -> bf16 + per-output-col sum (rowsum of W) --------
__global__ __launch_bounds__(256) void wconv_kernel(
    const float* __restrict__ W, unsigned short* __restrict__ Wb,
    float* __restrict__ wsum) {
  const int t = threadIdx.x;
  const size_t i = (size_t)blockIdx.x * 256 + t;  // float4 index
  float4 v = ((const float4*)W)[i];
  ushort4 o;
  o.x = f2bf(v.x); o.y = f2bf(v.y); o.z = f2bf(v.z); o.w = f2bf(v.w);
  ((ushort4*)Wb)[i] = o;
  const int row = (int)(i >> 9);  // W row = output feature (512 float4/row)
  float s = v.x + v.y + v.z + v.w;
#pragma unroll
  for (int off = 32; off > 0; off >>= 1) s += __shfl_down(s, off);
  if ((t & 63) == 0) atomicAdd(&wsum[row], s);  // wave-uniform row
}

// ---------------- fused LN+GEMM ------------------------------------------
// LDS per buf (64KB): A 32KB (256 rows x 128B, XOR-swizzled), B 32KB.
// A reg-stage: thread (g=tid>>4, c=tid&15) covers rows g*8+i (i=0..7),
// 16B fp32 chunk c -> 8B bf16 at swizzled slot (c>>1)^i within row.
// Per tile t head: BARR; VMC(0) [drains B(t)4 + gx(t+1)8]; reads of tile t
// issue; cvt gx->A(t+1) ds_writes; issue B(t+1) async16; issue gx(t+2).
// Stats: sS/sQ per (thread,i) accumulate x row sums during cvt.

#define BARR                                                           \
  do {                                                                 \
    __builtin_amdgcn_s_barrier();                                      \
    asm volatile("" ::: "memory");                                     \
  } while (0)

#define LGKM0                                                          \
  do {                                                                 \
    asm volatile("s_waitcnt lgkmcnt(0)" ::: "memory");                 \
    __builtin_amdgcn_sched_barrier(0);                                 \
  } while (0)

#define VMC0 asm volatile("s_waitcnt vmcnt(0)" ::: "memory")

#define LDGX(TT)                                                       \
  do {                                                                 \
    _Pragma("unroll") for (int i_ = 0; i_ < 8; ++i_)                   \
      gx[i_] = *(const float4*)(pX + (size_t)i_ * 2048 + (TT) * 64);   \
  } while (0)

#define CVW(BOFF)                                                      \
  do {                                                                 \
    _Pragma("unroll") for (int i_ = 0; i_ < 8; ++i_) {                 \
      float4 v_ = gx[i_];                                              \
      sS[i_] += v_.x + v_.y + v_.z + v_.w;                             \
      sQ[i_] += v_.x * v_.x + v_.y * v_.y + v_.z * v_.z + v_.w * v_.w; \
      b16x4 o_;                                                        \
      o_[0] = (__bf16)v_.x; o_[1] = (__bf16)v_.y;                      \
      o_[2] = (__bf16)v_.z; o_[3] = (__bf16)v_.w;                      \
      *(b16x4*)(lds + (BOFF) + wbA + i_ * 128 + ((slotc ^ i_) << 4)) = o_; \
    }                                                                  \
  } while (0)

#define STGB(BOFF, TT)                                                 \
  do {                                                                 \
    const char* s0_ = pB + (size_t)(TT) * 128;                         \
    char* d0_ = lds + (BOFF) + 32768 + tid * 16;                       \
    async16(d0_, s0_);                                                 \
    async16(d0_ + 8192, s0_ + (size_t)64 * 4096);                      \
    async16(d0_ + 16384, s0_ + (size_t)128 * 4096);                    \
    async16(d0_ + 24576, s0_ + (size_t)192 * 4096);                    \
  } while (0)

#define LDA_T(BOFF, QM, S)                                             \
  do {                                                                 \
    _Pragma("unroll") for (int i_ = 0; i_ < 4; ++i_) {                 \
      const char* p_ = lds + (BOFF) + (QM) * 16384 + abase + i_ * 2048; \
      aF[i_][S] = *(const b16x8*)(p_ + ((S) ? cs1 : cs0));             \
    }                                                                  \
  } while (0)

#define LDB_T(BOFF)                                                    \
  do {                                                                 \
    _Pragma("unroll") for (int n_ = 0; n_ < 4; ++n_) {                 \
      const char* p_ = lds + (BOFF) + bbase + (n_ >> 1) * 16384 + (n_ & 1) * 2048; \
      bF[n_][0] = *(const b16x8*)(p_ + cs0);                           \
      bF[n_][1] = *(const b16x8*)(p_ + cs1);                           \
    }                                                                  \
  } while (0)

#define MFMA_C(QM, S)                                                  \
  do {                                                                 \
    _Pragma("unroll") for (int i_ = 0; i_ < 4; ++i_) {                 \
      _Pragma("unroll") for (int n_ = 0; n_ < 4; ++n_) {               \
        acc[(QM) * 4 + i_][n_] = __builtin_amdgcn_mfma_f32_16x16x32_bf16( \
            aF[i_][S], bF[n_][S], acc[(QM) * 4 + i_][n_], 0, 0, 0);    \
      }                                                                \
    }                                                                  \
  } while (0)

__global__ __launch_bounds__(512, 2) void gemm_fln(
    const float* __restrict__ X, const unsigned short* __restrict__ Bw,
    const float* __restrict__ wsum, float* __restrict__ C) {
  __shared__ __align__(16) char lds[131072];

  const int bid0 = blockIdx.x;                       // 512 blocks
  const int bid = (bid0 & 7) * 64 + (bid0 >> 3);     // XCD swizzle (512%8==0)
  const int bm = bid >> 3;                           // 0..63
  const int bn = bid & 7;                            // 0..7

  const int tid = threadIdx.x;
  const int w = tid >> 6, l = tid & 63;
  const int wr = w >> 2, wc = w & 3;
  const int fr = l & 15, fg = l >> 4;

  // A reg-stage mapping: coalesced 16-lane row segments
  const int g = tid >> 4, c = tid & 15;
  const float* pX = X + (size_t)(bm * 256 + g * 8) * 2048 + c * 4;
  const int wbA = g * 1024 + (c & 1) * 8;
  const int slotc = c >> 1;

  // B staging source (linear dest, inverse-swizzled source) — proven R5 path
  const int arow = tid >> 3;
  const int swz = ((tid & 7) << 4) ^ ((arow & 7) << 4);
  const char* pB = (const char*)Bw + (size_t)(bn * 256 + arow) * 4096 + swz;

  // LDS read offsets (proven zero-conflict swizzle)
  const int cswz = (fg << 4) ^ ((fr & 7) << 4);
  const int cs0 = cswz, cs1 = cswz ^ 64;
  const int abase = (wr * 64 + fr) * 128;
  const int bbase = 32768 + (wc * 32 + fr) * 128;

  f32x4 acc[8][4] = {};
  b16x8 aF[4][2], bF[4][2];
  float4 gx[8];
  float sS[8] = {}, sQ[8] = {};

  // prologue: gx(0)->A(0)->buf0, B(0)->buf0, gx(1)
  LDGX(0);
  VMC0;
  CVW(0);
  STGB(0, 0);
  LDGX(1);
  LGKM0;

#pragma unroll 1
  for (int t = 0; t < 32; ++t) {
    const int cur = (t & 1) << 16;
    const int nxt = 65536 - cur;
    BARR;
    VMC0;                      // B(t) + gx(t+1) landed (issued a full tile ago)
    LDA_T(cur, 0, 0); LDA_T(cur, 0, 1);
    LDB_T(cur);
    if (t < 31) { CVW(nxt); STGB(nxt, t + 1); }
    if (t < 30) { LDGX(t + 2); }
    __builtin_amdgcn_s_setprio(1);
    MFMA_C(0, 0);
    MFMA_C(0, 1);
    LDA_T(cur, 1, 0); LDA_T(cur, 1, 1);
    MFMA_C(1, 0);
    MFMA_C(1, 1);
    __builtin_amdgcn_s_setprio(0);
    LGKM0;                     // drain A-writes (+reads) before next barrier
  }

  // stats: reduce over the 16 chunk-lanes, publish (mu, rs) per row in LDS
#pragma unroll
  for (int i = 0; i < 8; ++i) {
#pragma unroll
    for (int m = 1; m < 16; m <<= 1) {
      sS[i] += __shfl_xor(sS[i], m);
      sQ[i] += __shfl_xor(sQ[i], m);
    }
  }
  if (c == 0) {
#pragma unroll
    for (int i = 0; i < 8; ++i) {
      const float mu = sS[i] * (1.0f / 2048.0f);
      const float va = fmaxf(sQ[i] * (1.0f / 2048.0f) - mu * mu, 0.0f);
      const float rs = rsqrtf(va + 1e-5f);
      *(float2*)(lds + (g * 8 + i) * 8) = make_float2(mu, rs);
    }
  }
  LGKM0;
  BARR;

  // epilogue: y = rs*(acc - mu*wsum_col), sigmoid, store.
  const float* wsp = wsum + bn * 256 + wc * 32 + fr;
  float wsv[4];
#pragma unroll
  for (int n = 0; n < 4; ++n) wsv[n] = wsp[(n >> 1) * 128 + (n & 1) * 16];
  float* gC = C + (size_t)(bm * 256) * 2048 + bn * 256;
#pragma unroll
  for (int qm = 0; qm < 2; ++qm) {
#pragma unroll
    for (int i = 0; i < 4; ++i) {
#pragma unroll
      for (int n = 0; n < 4; ++n) {
        const int col = (n >> 1) * 128 + wc * 32 + (n & 1) * 16 + fr;
#pragma unroll
        for (int r = 0; r < 4; ++r) {
          const int row = qm * 128 + wr * 64 + i * 16 + fg * 4 + r;
          const float2 ln = *(const float2*)(lds + row * 8);
          const float y = ln.y * (acc[qm * 4 + i][n][r] - ln.x * wsv[n]);
          gC[(size_t)row * 2048 + col] =
              __builtin_amdgcn_rcpf(1.0f + __expf(-y));
        }
      }
    }
  }
}

extern "C" void kernel_launch(void* const* d_in, const int* in_sizes, int n_in,
                              void* d_out, int out_size, void* d_ws, size_t ws_size,
                              hipStream_t stream) {
  const float* x = (const float*)d_in[0];
  const float* W = (const float*)d_in[1];
  float* out = (float*)d_out;

  unsigned short* Wb = (unsigned short*)d_ws;
  float* wsum = (float*)((char*)d_ws + (size_t)2048 * 2048 * 2);

  hipMemsetAsync(wsum, 0, 2048 * sizeof(float), stream);
  wconv_kernel<<<4096, 256, 0, stream>>>(W, Wb, wsum);
  gemm_fln<<<512, 512, 0, stream>>>(x, Wb, wsum, out);
}

// Round 10
// 158.966 us; speedup vs baseline: 4.5467x; 4.5467x over previous
//
#include <hip/hip_runtime.h>
#include <hip/hip_bf16.h>
#include <stdint.h>

// LNLinearSigmoid: LayerNorm(x) @ W^T -> sigmoid
// Round 10: revert to R5 champion (256x256, 8-phase, 1 barrier/phase,
// 16x16x32 MFMA, zero-conflict XOR swizzle, vmcnt(6)) + ALL ds_reads moved
// inside MFMA clusters via bF0/bF1 role alternation (liveness-verified).
// Stage map / barriers / vmcnt ledger identical to R5. ws >= 75.5 MB.

typedef __attribute__((ext_vector_type(4))) float f32x4;
typedef __attribute__((ext_vector_type(8))) __bf16 b16x8;

__device__ __forceinline__ void async16(void* lds_p, const void* g) {
  __builtin_amdgcn_global_load_lds(
      (const __attribute__((address_space(1))) void*)g,
      (__attribute__((address_space(3))) void*)lds_p, 16, 0, 0);
}

__device__ __forceinline__ unsigned short f2bf(float f) {
  uint32_t u = __float_as_uint(f);
  u += 0x7FFFu + ((u >> 16) & 1u);
  return (unsigned short)(u >> 16);
}

// ---------------- LN (blocks 0..16383) + W conv (blocks 16384..20479) ------
__global__ __launch_bounds__(256) void ln_wconv_kernel(
    const float* __restrict__ x, unsigned short* __restrict__ xn,
    const float* __restrict__ W, unsigned short* __restrict__ Wb) {
  const int t = threadIdx.x;
  if (blockIdx.x >= 16384) {
    const size_t i = (size_t)(blockIdx.x - 16384) * 256 + t;
    float4 v = ((const float4*)W)[i];
    ushort4 o;
    o.x = f2bf(v.x); o.y = f2bf(v.y); o.z = f2bf(v.z); o.w = f2bf(v.w);
    ((ushort4*)Wb)[i] = o;
    return;
  }
  const int row = blockIdx.x;
  const float4* xr = (const float4*)(x + (size_t)row * 2048);
  float4 a = xr[t];
  float4 b = xr[t + 256];
  float s = a.x + a.y + a.z + a.w + b.x + b.y + b.z + b.w;
  float q = a.x * a.x + a.y * a.y + a.z * a.z + a.w * a.w +
            b.x * b.x + b.y * b.y + b.z * b.z + b.w * b.w;
#pragma unroll
  for (int off = 32; off > 0; off >>= 1) {
    s += __shfl_down(s, off);
    q += __shfl_down(q, off);
  }
  __shared__ float red[8];
  const int w = t >> 6;
  if ((t & 63) == 0) { red[w] = s; red[4 + w] = q; }
  __syncthreads();
  s = red[0] + red[1] + red[2] + red[3];
  q = red[4] + red[5] + red[6] + red[7];
  const float mean = s * (1.0f / 2048.0f);
  const float var = fmaxf(q * (1.0f / 2048.0f) - mean * mean, 0.0f);
  const float scl = rsqrtf(var + 1e-5f);
  ushort4 o0, o1;
  o0.x = f2bf((a.x - mean) * scl);
  o0.y = f2bf((a.y - mean) * scl);
  o0.z = f2bf((a.z - mean) * scl);
  o0.w = f2bf((a.w - mean) * scl);
  o1.x = f2bf((b.x - mean) * scl);
  o1.y = f2bf((b.y - mean) * scl);
  o1.z = f2bf((b.z - mean) * scl);
  o1.w = f2bf((b.w - mean) * scl);
  ushort4* orow = (ushort4*)(xn + (size_t)row * 2048);
  orow[t] = o0;
  orow[t + 256] = o1;
}

// ---------------- 256x256 8-phase GEMM, reads fully inside MFMA ------------
// LDS: buf*65536 + {A0:0, A1:16K, B0:32K, B1:48K}. Regions 128 rows x 128B.
// Stage map (= R5): P1:A1->buf1(t1) P2:B0->buf0(t2) P3:A0->buf0(t2)
//   P4:B1->buf0(t2) P5:A1->buf0(t2) P6:B0->buf1(t3) P7:A0->buf1(t3)
//   P8:B1->buf1(t3). vmcnt(6) at P4/P8 (mid-cluster).
// bF roles per iter: P1:bF0 (ld bF1<-buf0.B1); P2,P3:bF1; P4:bF0
//   (mid: VMC, ld aF<-buf1.A0, bF1<-buf1.B0); P5:bF1 (ld bF0<-buf1.B1);
//   P6,P7:bF0; P8:bF1 (mid: VMC, ld aF<-buf0.A0, bF0<-buf0.B0).

#define STG_A(buf, h, kt)                                              \
  do {                                                                 \
    const char* s_ = pA + (size_t)((h) * 128) * 4096 + (kt) * 128;     \
    char* d_ = lds + (buf) * 65536 + (h) * 16384 + tid * 16;           \
    async16(d_, s_);                                                   \
    async16(d_ + 8192, s_ + 64 * 4096);                                \
  } while (0)

#define STG_B(buf, h, kt)                                              \
  do {                                                                 \
    const char* s_ = pB + (size_t)((h) * 128) * 4096 + (kt) * 128;     \
    char* d_ = lds + 32768 + (buf) * 65536 + (h) * 16384 + tid * 16;   \
    async16(d_, s_);                                                   \
    async16(d_ + 8192, s_ + 64 * 4096);                                \
  } while (0)

#define LDA_S(buf, qm, S)                                              \
  do {                                                                 \
    _Pragma("unroll") for (int i_ = 0; i_ < 4; ++i_) {                 \
      const char* p_ = lds + (buf) * 65536 + (qm) * 16384 + abase + i_ * 2048; \
      aF[i_][S] = *(const b16x8*)(p_ + ((S) ? cs1 : cs0));             \
    }                                                                  \
  } while (0)

#define LDB_S(dstf, buf, qn, S)                                        \
  do {                                                                 \
    _Pragma("unroll") for (int j_ = 0; j_ < 2; ++j_) {                 \
      const char* p_ = lds + (buf) * 65536 + (qn) * 16384 + bbase + j_ * 2048; \
      dstf[j_][S] = *(const b16x8*)(p_ + ((S) ? cs1 : cs0));           \
    }                                                                  \
  } while (0)

#define MFMA_H(qm, qn, BF, S)                                          \
  do {                                                                 \
    __builtin_amdgcn_s_setprio(1);                                     \
    _Pragma("unroll") for (int i_ = 0; i_ < 4; ++i_) {                 \
      _Pragma("unroll") for (int j_ = 0; j_ < 2; ++j_) {               \
        acc[(qm) * 4 + i_][(qn) * 2 + j_] =                            \
            __builtin_amdgcn_mfma_f32_16x16x32_bf16(                   \
                aF[i_][S], BF[j_][S], acc[(qm) * 4 + i_][(qn) * 2 + j_], 0, 0, 0); \
      }                                                                \
    }                                                                  \
    __builtin_amdgcn_s_setprio(0);                                     \
  } while (0)

#define MFMA_Q(qm, qn, BF)                                             \
  do { MFMA_H(qm, qn, BF, 0); MFMA_H(qm, qn, BF, 1); } while (0)

#define BARR                                                           \
  do {                                                                 \
    __builtin_amdgcn_s_barrier();                                      \
    asm volatile("" ::: "memory");                                     \
  } while (0)

#define LGKM0                                                          \
  do {                                                                 \
    asm volatile("s_waitcnt lgkmcnt(0)" ::: "memory");                 \
    __builtin_amdgcn_sched_barrier(0);                                 \
  } while (0)

#define SB0 __builtin_amdgcn_sched_barrier(0)
#define VMC(n) asm volatile("s_waitcnt vmcnt(" #n ")" ::: "memory")

__global__ __launch_bounds__(512, 2) void gemm8p(
    const unsigned short* __restrict__ A, const unsigned short* __restrict__ B,
    float* __restrict__ C) {
  __shared__ __align__(16) char lds[131072];

  const int bid0 = blockIdx.x;                       // 512 blocks
  const int bid = (bid0 & 7) * 64 + (bid0 >> 3);     // XCD swizzle (512%8==0)
  const int bm = bid >> 3;                           // 0..63
  const int bn = bid & 7;                            // 0..7

  const int tid = threadIdx.x;
  const int w = tid >> 6, l = tid & 63;
  const int wr = w >> 2, wc = w & 3;
  const int fr = l & 15, fg = l >> 4;

  // staging source (linear LDS dest, inverse-swizzled global source)
  const int arow = tid >> 3;
  const int swz = ((tid & 7) << 4) ^ ((arow & 7) << 4);
  const char* pA = (const char*)A + (size_t)(bm * 256 + arow) * 4096 + swz;
  const char* pB = (const char*)B + (size_t)(bn * 256 + arow) * 4096 + swz;

  // ds_read offsets (proven zero-conflict swizzle)
  const int cswz = (fg << 4) ^ ((fr & 7) << 4);
  const int cs0 = cswz, cs1 = cswz ^ 64;
  const int abase = (wr * 64 + fr) * 128;
  const int bbase = 32768 + (wc * 32 + fr) * 128;

  f32x4 acc[8][4] = {};
  b16x8 aF[4][2], bF0[2][2], bF1[2][2];

  // prologue: t0 full -> buf0; t1: B0,A0,B1 -> buf1
  STG_A(0, 0, 0); STG_B(0, 0, 0); STG_B(0, 1, 0); STG_A(0, 1, 0);
  STG_B(1, 0, 1); STG_A(1, 0, 1); STG_B(1, 1, 1);
  VMC(6);
  BARR;
  LDA_S(0, 0, 0); LDA_S(0, 0, 1);
  LDB_S(bF0, 0, 0, 0); LDB_S(bF0, 0, 0, 1);   // P1@it0 operands

#pragma unroll 1
  for (int it = 0; it < 16; ++it) {
    const int t1 = 2 * it + 1, t2 = 2 * it + 2, t3 = 2 * it + 3;
    const bool s2 = (it < 15);

    // P1: Q(0,0) buf0, B=bF0. Load bF1<-buf0.B1 inside cluster.
    STG_A(1, 1, t1);
    BARR; LGKM0;
    MFMA_H(0, 0, bF0, 0);
    SB0; LDB_S(bF1, 0, 1, 0); SB0;
    MFMA_H(0, 0, bF0, 1);
    SB0; LDB_S(bF1, 0, 1, 1);

    // P2: Q(0,1) buf0, B=bF1. Refill aF<-buf0.A1.
    if (s2) STG_B(0, 0, t2);
    BARR; LGKM0;
    MFMA_H(0, 1, bF1, 0);
    SB0; LDA_S(0, 1, 0); SB0;
    MFMA_H(0, 1, bF1, 1);
    SB0; LDA_S(0, 1, 1);

    // P3: Q(1,1) buf0, B=bF1 (aF = buf0.A1).
    if (s2) STG_A(0, 0, t2);
    BARR; LGKM0;
    MFMA_Q(1, 1, bF1);

    // P4: Q(1,0) buf0, B=bF0. Mid: VMC; aF<-buf1.A0, bF1<-buf1.B0.
    if (s2) STG_B(0, 1, t2);
    BARR; LGKM0;
    MFMA_H(1, 0, bF0, 0);
    if (s2) { VMC(6); } else { VMC(0); }
    SB0; LDA_S(1, 0, 0); LDB_S(bF1, 1, 0, 0); SB0;
    MFMA_H(1, 0, bF0, 1);
    SB0; LDA_S(1, 0, 1); LDB_S(bF1, 1, 0, 1);

    // P5: Q(0,0) buf1, B=bF1. Load bF0<-buf1.B1 inside cluster.
    if (s2) STG_A(0, 1, t2);
    BARR; LGKM0;
    MFMA_H(0, 0, bF1, 0);
    SB0; LDB_S(bF0, 1, 1, 0); SB0;
    MFMA_H(0, 0, bF1, 1);
    SB0; LDB_S(bF0, 1, 1, 1);

    // P6: Q(0,1) buf1, B=bF0. Refill aF<-buf1.A1.
    if (s2) STG_B(1, 0, t3);
    BARR; LGKM0;
    MFMA_H(0, 1, bF0, 0);
    SB0; LDA_S(1, 1, 0); SB0;
    MFMA_H(0, 1, bF0, 1);
    SB0; LDA_S(1, 1, 1);

    // P7: Q(1,1) buf1, B=bF0.
    if (s2) STG_A(1, 0, t3);
    BARR; LGKM0;
    MFMA_Q(1, 1, bF0);

    // P8: Q(1,0) buf1, B=bF1. Mid: VMC(6); aF<-buf0.A0, bF0<-buf0.B0.
    if (s2) STG_B(1, 1, t3);
    BARR; LGKM0;
    MFMA_H(1, 0, bF1, 0);
    if (s2) { VMC(6); SB0; LDA_S(0, 0, 0); LDB_S(bF0, 0, 0, 0); SB0; }
    MFMA_H(1, 0, bF1, 1);
    if (s2) { SB0; LDA_S(0, 0, 1); LDB_S(bF0, 0, 0, 1); }
  }

  // epilogue: sigmoid + store. C/D frag: row = fg*4 + r, col = fr.
  float* gC = C + (size_t)(bm * 256) * 2048 + bn * 256;
#pragma unroll
  for (int qm = 0; qm < 2; ++qm) {
#pragma unroll
    for (int i = 0; i < 4; ++i) {
#pragma unroll
      for (int qn = 0; qn < 2; ++qn) {
#pragma unroll
        for (int j = 0; j < 2; ++j) {
#pragma unroll
          for (int r = 0; r < 4; ++r) {
            const int row = qm * 128 + wr * 64 + i * 16 + fg * 4 + r;
            const int col = qn * 128 + wc * 32 + j * 16 + fr;
            const float y = acc[qm * 4 + i][qn * 2 + j][r];
            gC[(size_t)row * 2048 + col] =
                __builtin_amdgcn_rcpf(1.0f + __expf(-y));
          }
        }
      }
    }
  }
}

extern "C" void kernel_launch(void* const* d_in, const int* in_sizes, int n_in,
                              void* d_out, int out_size, void* d_ws, size_t ws_size,
                              hipStream_t stream) {
  const float* x = (const float*)d_in[0];
  const float* W = (const float*)d_in[1];
  float* out = (float*)d_out;

  unsigned short* xnb = (unsigned short*)d_ws;
  unsigned short* Wb =
      (unsigned short*)((char*)d_ws + (size_t)16384 * 2048 * 2);

  ln_wconv_kernel<<<16384 + 4096, 256, 0, stream>>>(x, xnb, W, Wb);
  gemm8p<<<512, 512, 0, stream>>>(xnb, Wb, out);
}